// Round 4
// baseline (627.986 us; speedup 1.0000x reference)
//
#include <hip/hip_runtime.h>
#include <math.h>

#define EPSV 1e-8f

// d_out layout (floats): ntm_out[0], memory[65536], read_out[33619968],
// new_read_w[33685504], new_write_w[35782656]
#define O_MEM 65536
#define O_RO  33619968
#define O_NRW 33685504
#define O_NWW 35782656

__device__ __forceinline__ float sp_(float x){ return fmaxf(x,0.f) + log1pf(expf(-fabsf(x))); }
__device__ __forceinline__ float sg_(float x){ return 1.f/(1.f+expf(-x)); }

// ---------------- fused controller + projections + ntm_out partial ----------
// grid 256 (1 batch/block), 512 threads.
struct CM { const float* P; int S; float bv; float* dst; };

__device__ __forceinline__ CM cmap(int c, int b,
    const float* __restrict__ rW, const float* __restrict__ rB,
    const float* __restrict__ wW, const float* __restrict__ wB,
    const float* __restrict__ oW,
    float* __restrict__ rp, float* __restrict__ wp, float* __restrict__ out)
{
  CM m;
  if (c < 280){
    int h = c/70, j = c - h*70;
    m.P = rW + (size_t)h*35840 + j;  m.S = 70;
    m.bv = rB[c];
    m.dst = rp + ((size_t)h*256 + b)*70 + j;
  } else if (c < 1072){
    int c2 = c - 280, h = c2/198, j = c2 - h*198;
    m.P = wW + (size_t)h*101376 + j; m.S = 198;
    m.bv = wB[c2];
    m.dst = wp + ((size_t)h*256 + b)*198 + j;
  } else {
    int j = c - 1072;
    m.P = oW + j;                    m.S = 256;
    m.bv = 0.f;
    m.dst = out + (size_t)b*256 + j;
  }
  return m;
}

__global__ __launch_bounds__(512) void k_proj(
    const float* __restrict__ ext, const float* __restrict__ prd,
    const float* __restrict__ cW, const float* __restrict__ cB,
    const float* __restrict__ rW, const float* __restrict__ rB,
    const float* __restrict__ wW, const float* __restrict__ wB,
    const float* __restrict__ oW,
    float* __restrict__ rp, float* __restrict__ wp, float* __restrict__ out)
{
  __shared__ float ins[512];
  __shared__ float cs[512];
  const int t = threadIdx.x, b = blockIdx.x;
  ins[t] = (t < 256) ? ext[(size_t)b*256 + t] : prd[(size_t)b*256 + (t - 256)];
  __syncthreads();

  { // phase 1: ctrl col t, 4 split accumulators for ILP
    float a0=0.f, a1=0.f, a2=0.f, a3=0.f;
    const float* W = cW + t;
    #pragma unroll 4
    for (int k=0; k<512; k+=4){
      float4 iv = *(const float4*)&ins[k];
      a0 = fmaf(iv.x, W[(k+0)*512], a0);
      a1 = fmaf(iv.y, W[(k+1)*512], a1);
      a2 = fmaf(iv.z, W[(k+2)*512], a2);
      a3 = fmaf(iv.w, W[(k+3)*512], a3);
    }
    cs[t] = (a0+a1)+(a2+a3) + cB[t];
  }
  __syncthreads();

  { // phase 2: cols t and t+512 paired
    CM m0 = cmap(t,       b, rW,rB,wW,wB,oW, rp,wp,out);
    CM m1 = cmap(t + 512, b, rW,rB,wW,wB,oW, rp,wp,out);
    const float* P0 = m0.P; const int S0 = m0.S;
    const float* P1 = m1.P; const int S1 = m1.S;
    float a00=0.f,a01=0.f,a02=0.f,a03=0.f;
    float a10=0.f,a11=0.f,a12=0.f,a13=0.f;
    #pragma unroll 4
    for (int k=0; k<512; k+=4){
      float4 cv = *(const float4*)&cs[k];
      a00 = fmaf(cv.x, P0[(k+0)*S0], a00);
      a10 = fmaf(cv.x, P1[(k+0)*S1], a10);
      a01 = fmaf(cv.y, P0[(k+1)*S0], a01);
      a11 = fmaf(cv.y, P1[(k+1)*S1], a11);
      a02 = fmaf(cv.z, P0[(k+2)*S0], a02);
      a12 = fmaf(cv.z, P1[(k+2)*S1], a12);
      a03 = fmaf(cv.w, P0[(k+3)*S0], a03);
      a13 = fmaf(cv.w, P1[(k+3)*S1], a13);
    }
    *m0.dst = (a00+a01)+(a02+a03) + m0.bv;
    *m1.dst = (a10+a11)+(a12+a13) + m1.bv;

    if (t < 304){ // tail: cols 1024..1327
      CM m2 = cmap(t + 1024, b, rW,rB,wW,wB,oW, rp,wp,out);
      const float* P2 = m2.P; const int S2 = m2.S;
      float b0=0.f,b1=0.f,b2=0.f,b3=0.f;
      #pragma unroll 4
      for (int k=0; k<512; k+=4){
        float4 cv = *(const float4*)&cs[k];
        b0 = fmaf(cv.x, P2[(k+0)*S2], b0);
        b1 = fmaf(cv.y, P2[(k+1)*S2], b1);
        b2 = fmaf(cv.z, P2[(k+2)*S2], b2);
        b3 = fmaf(cv.w, P2[(k+3)*S2], b3);
      }
      *m2.dst = (b0+b1)+(b2+b3) + m2.bv;
    }
  }
}

// ---------------- mega kernel (1024 threads) --------------------------------

__device__ __forceinline__ float blockMax(float v, float* red){
  #pragma unroll
  for (int o=32;o;o>>=1) v = fmaxf(v, __shfl_down(v,o,64));
  __syncthreads();
  if ((threadIdx.x & 63) == 0) red[threadIdx.x>>6] = v;
  __syncthreads();
  float m = red[0];
  #pragma unroll
  for (int i=1;i<16;i++) m = fmaxf(m, red[i]);
  return m;
}
__device__ __forceinline__ float blockSum(float v, float* red){
  #pragma unroll
  for (int o=32;o;o>>=1) v += __shfl_down(v,o,64);
  __syncthreads();
  if ((threadIdx.x & 63) == 0) red[threadIdx.x>>6] = v;
  __syncthreads();
  float s = red[0];
  #pragma unroll
  for (int i=1;i<16;i++) s += red[i];
  return s;
}

// NTM addressing over slot c[2048]. 1024 thr, 2 elems/thread.
__device__ void addressing(float* c, const float* __restrict__ wprev, float* __restrict__ wout,
                           float beta, float g, float s0, float s1, float s2, float gam,
                           float* red, int t){
  int base = t*2;
  float lv0, lv1;
  {
    float2 cv = *(const float2*)&c[base];
    lv0 = beta*cv.x; lv1 = beta*cv.y;
  }
  float mx = blockMax(fmaxf(lv0,lv1), red);
  lv0 = expf(lv0-mx); lv1 = expf(lv1-mx);
  float sm = blockSum(lv0+lv1, red);
  float inv = 1.f/sm;
  float gi = 1.f - g;
  {
    float2 wp2 = *(const float2*)&wprev[base];
    lv0 = g*lv0*inv + gi*wp2.x;
    lv1 = g*lv1*inv + gi*wp2.y;
  }
  *(float2*)&c[base] = make_float2(lv0, lv1);
  __syncthreads();
  float left  = c[(base+2047)&2047];
  float right = c[(base+2)&2047];
  __syncthreads();
  float ws0 = s0*lv1   + s1*lv0 + s2*left;
  float ws1 = s0*right + s1*lv1 + s2*lv0;
  float pw0 = expf(gam * logf(ws0 + EPSV));
  float pw1 = expf(gam * logf(ws1 + EPSV));
  float ps = blockSum(pw0+pw1, red);
  float invp = 1.f/ps;
  float2 wo = make_float2(pw0*invp, pw1*invp);
  *(float2*)&c[base] = wo;
  *(float2*)&wout[base] = wo;
  __syncthreads();
}

// Streaming cos pass: 4 lanes/row, 256 rows/iter, 8 iters, NO internal barriers.
template<int NUPD, int NCOS, int KS0>
__device__ __forceinline__ void cos_pass(const float* __restrict__ gmb,
    float (*slots)[2048], const float* __restrict__ kr, const float* __restrict__ kw,
    const float* __restrict__ er, const float* __restrict__ aw,
    const float* __restrict__ kn, int t)
{
  const int row0 = t>>2, q = t&3, cb = q<<4;
  float4 kk[NCOS][4];
  float knl[NCOS];
  #pragma unroll
  for (int c=0;c<NCOS;c++){
    const int ks = (NCOS==5)? c : KS0;
    const float* kb = (ks<4)? (kr + ks*64) : (kw + (ks-4)*64);
    #pragma unroll
    for (int j=0;j<4;j++) kk[c][j] = *(const float4*)&kb[cb + 4*j];
    knl[c] = kn[ks];
  }
  float4 ee[NUPD>0?NUPD:1][4], aa[NUPD>0?NUPD:1][4];
  #pragma unroll
  for (int h=0;h<NUPD;h++){
    #pragma unroll
    for (int j=0;j<4;j++){
      ee[h][j] = *(const float4*)&er[h*64+cb+4*j];
      aa[h][j] = *(const float4*)&aw[h*64+cb+4*j];
    }
  }
  #pragma unroll 4
  for (int it=0; it<8; ++it){
    const int row = (it<<8) + row0;
    const float4* src = (const float4*)(gmb + ((size_t)row<<6) + cb);
    float4 v[4];
    #pragma unroll
    for (int j=0;j<4;j++) v[j] = src[j];
    #pragma unroll
    for (int h=0;h<NUPD;h++){
      float w = slots[4+h][row];
      #pragma unroll
      for (int j=0;j<4;j++){
        v[j].x = fmaf(-w, fmaf(v[j].x, ee[h][j].x, -aa[h][j].x), v[j].x);
        v[j].y = fmaf(-w, fmaf(v[j].y, ee[h][j].y, -aa[h][j].y), v[j].y);
        v[j].z = fmaf(-w, fmaf(v[j].z, ee[h][j].z, -aa[h][j].z), v[j].z);
        v[j].w = fmaf(-w, fmaf(v[j].w, ee[h][j].w, -aa[h][j].w), v[j].w);
      }
    }
    float nrm = 0.f;
    float acc[NCOS];
    #pragma unroll
    for (int c=0;c<NCOS;c++) acc[c]=0.f;
    #pragma unroll
    for (int j=0;j<4;j++){
      nrm = fmaf(v[j].x,v[j].x, fmaf(v[j].y,v[j].y, fmaf(v[j].z,v[j].z, fmaf(v[j].w,v[j].w, nrm))));
      #pragma unroll
      for (int c=0;c<NCOS;c++){
        acc[c] = fmaf(v[j].x,kk[c][j].x, fmaf(v[j].y,kk[c][j].y,
                  fmaf(v[j].z,kk[c][j].z, fmaf(v[j].w,kk[c][j].w, acc[c]))));
      }
    }
    nrm += __shfl_xor(nrm,1); nrm += __shfl_xor(nrm,2);
    #pragma unroll
    for (int c=0;c<NCOS;c++){ acc[c] += __shfl_xor(acc[c],1); acc[c] += __shfl_xor(acc[c],2); }
    float mn = sqrtf(nrm);
    if (NCOS==5){
      float av = acc[0], kv = knl[0];
      #pragma unroll
      for (int c=1;c<4;c++){ if (q==c){ av=acc[c]; kv=knl[c]; } }
      slots[q][row] = av/(mn*kv+EPSV);
      if (q==0) slots[4][row] = acc[NCOS-1]/(mn*knl[NCOS-1]+EPSV);
    } else {
      if (q==0) slots[KS0][row] = acc[0]/(mn*knl[0]+EPSV);
    }
  }
}

// Final pass: 8 lanes/row, 128 rows/iter, 16 iters. Reads raw rows, accumulates
// read vectors, applies 4 updates, writes final memory.
__device__ __forceinline__ void final_pass(const float* __restrict__ gmb,
    float (*slots)[2048], const float* __restrict__ er, const float* __restrict__ aw,
    float4 racc[4][2], float* __restrict__ gout, int t)
{
  const int row0 = t>>3, q = t&7, cb = q<<3;
  float4 ee[4][2], aa[4][2];
  #pragma unroll
  for (int h=0;h<4;h++){
    #pragma unroll
    for (int j=0;j<2;j++){
      ee[h][j] = *(const float4*)&er[h*64+cb+4*j];
      aa[h][j] = *(const float4*)&aw[h*64+cb+4*j];
    }
  }
  #pragma unroll 4
  for (int it=0; it<16; ++it){
    const int row = (it<<7) + row0;
    const float4* src = (const float4*)(gmb + ((size_t)row<<6) + cb);
    float4 v0 = src[0], v1 = src[1];
    #pragma unroll
    for (int h=0;h<4;h++){
      float wr = slots[h][row];
      racc[h][0].x = fmaf(wr, v0.x, racc[h][0].x);
      racc[h][0].y = fmaf(wr, v0.y, racc[h][0].y);
      racc[h][0].z = fmaf(wr, v0.z, racc[h][0].z);
      racc[h][0].w = fmaf(wr, v0.w, racc[h][0].w);
      racc[h][1].x = fmaf(wr, v1.x, racc[h][1].x);
      racc[h][1].y = fmaf(wr, v1.y, racc[h][1].y);
      racc[h][1].z = fmaf(wr, v1.z, racc[h][1].z);
      racc[h][1].w = fmaf(wr, v1.w, racc[h][1].w);
    }
    #pragma unroll
    for (int h=0;h<4;h++){
      float w = slots[4+h][row];
      v0.x = fmaf(-w, fmaf(v0.x, ee[h][0].x, -aa[h][0].x), v0.x);
      v0.y = fmaf(-w, fmaf(v0.y, ee[h][0].y, -aa[h][0].y), v0.y);
      v0.z = fmaf(-w, fmaf(v0.z, ee[h][0].z, -aa[h][0].z), v0.z);
      v0.w = fmaf(-w, fmaf(v0.w, ee[h][0].w, -aa[h][0].w), v0.w);
      v1.x = fmaf(-w, fmaf(v1.x, ee[h][1].x, -aa[h][1].x), v1.x);
      v1.y = fmaf(-w, fmaf(v1.y, ee[h][1].y, -aa[h][1].y), v1.y);
      v1.z = fmaf(-w, fmaf(v1.z, ee[h][1].z, -aa[h][1].z), v1.z);
      v1.w = fmaf(-w, fmaf(v1.w, ee[h][1].w, -aa[h][1].w), v1.w);
    }
    float4* dst = (float4*)(gout + ((size_t)row<<6) + cb);
    dst[0]=v0; dst[1]=v1;
  }
}

__global__ __launch_bounds__(1024) void mega_kernel(
    const float* __restrict__ mem0, const float* __restrict__ prw, const float* __restrict__ pww,
    const float* __restrict__ rp, const float* __restrict__ wp,
    const float* __restrict__ oW, const float* __restrict__ oB, float* __restrict__ out)
{
  const int b = blockIdx.x, t = threadIdx.x;
  __shared__ float slots[8][2048];   // 64 KB: 0-3 cos_r->w_r ; 4-7 cos_w->w_w
  __shared__ float kr[256], kw[256], er[256], aw[256];
  __shared__ float sBeta[8], sG[8], sGam[8], sKn[8], sS0[8], sS1[8], sS2[8];
  __shared__ float red[16];
  __shared__ float ro[256];          // read_out for the ntm_out epilogue

  if (t < 256){ // activations: idx 0-3 read heads, 4-7 write heads
    int h = t>>6, m = t&63;
    kr[t] = rp[((size_t)h*256 + b)*70 + m];
    const float* wph = wp + ((size_t)h*256 + b)*198;
    kw[t] = wph[m];
    er[t] = sg_(wph[70+m]);
    aw[t] = tanhf(wph[134+m]);
    if (t < 8){
      int hh = t & 3;
      const float* p = (t>=4) ? (wp + ((size_t)hh*256+b)*198) : (rp + ((size_t)hh*256+b)*70);
      sBeta[t] = sp_(p[64]);
      sG[t]    = sg_(p[65]);
      float a0=p[66], a1=p[67], a2=p[68];
      float mx = fmaxf(a0, fmaxf(a1,a2));
      float e0=expf(a0-mx), e1=expf(a1-mx), e2=expf(a2-mx);
      float inv = 1.f/(e0+e1+e2);
      sS0[t]=e0*inv; sS1[t]=e1*inv; sS2[t]=e2*inv;
      sGam[t]  = 1.f + sp_(p[69]);
    }
  }
  __syncthreads();
  if (t < 8){
    const float* kv = (t>=4) ? (kw + (t&3)*64) : (kr + (t&3)*64);
    float s=0.f;
    for (int m=0;m<64;m++) s = fmaf(kv[m],kv[m],s);
    sKn[t] = sqrtf(s);
  }
  __syncthreads();

  const float* gmb = mem0 + (size_t)b*131072;

  // Pass A: cos for read heads 0-3 (slots 0-3) + write head 0 (slot 4)
  cos_pass<0,5,0>(gmb, slots, kr,kw,er,aw,sKn, t);
  __syncthreads();
  #pragma unroll 1
  for (int h=0;h<4;h++)
    addressing(slots[h], prw + ((size_t)h*256+b)*2048, out + O_NRW + ((size_t)h*256+b)*2048,
               sBeta[h], sG[h], sS0[h], sS1[h], sS2[h], sGam[h], red, t);
  addressing(slots[4], pww + (size_t)b*2048, out + O_NWW + (size_t)b*2048,
             sBeta[4], sG[4], sS0[4], sS1[4], sS2[4], sGam[4], red, t);

  // Pass 1: update{0} -> cos_w1 (slot 5)
  cos_pass<1,1,5>(gmb, slots, kr,kw,er,aw,sKn, t);
  __syncthreads();
  addressing(slots[5], pww + ((size_t)256+b)*2048, out + O_NWW + ((size_t)256+b)*2048,
             sBeta[5], sG[5], sS0[5], sS1[5], sS2[5], sGam[5], red, t);

  // Pass 2: updates{0,1} -> cos_w2 (slot 6)
  cos_pass<2,1,6>(gmb, slots, kr,kw,er,aw,sKn, t);
  __syncthreads();
  addressing(slots[6], pww + ((size_t)512+b)*2048, out + O_NWW + ((size_t)512+b)*2048,
             sBeta[6], sG[6], sS0[6], sS1[6], sS2[6], sGam[6], red, t);

  // Pass 3: updates{0,1,2} -> cos_w3 (slot 7)
  cos_pass<3,1,7>(gmb, slots, kr,kw,er,aw,sKn, t);
  __syncthreads();
  addressing(slots[7], pww + ((size_t)768+b)*2048, out + O_NWW + ((size_t)768+b)*2048,
             sBeta[7], sG[7], sS0[7], sS1[7], sS2[7], sGam[7], red, t);

  // Final pass: reads on raw rows + all 4 updates + write memory
  float4 racc[4][2];
  #pragma unroll
  for (int h=0;h<4;h++){ racc[h][0]=make_float4(0,0,0,0); racc[h][1]=make_float4(0,0,0,0); }
  final_pass(gmb, slots, er, aw, racc, out + O_MEM + (size_t)b*131072, t);
  __syncthreads();

  // reads reduction: thread t = row0*8+q holds cols q*8..q*8+7 partials
  {
    float* scr = (float*)slots;
    #pragma unroll 1
    for (int h=0;h<4;h++){
      *(float4*)&scr[t*8]   = racc[h][0];
      *(float4*)&scr[t*8+4] = racc[h][1];
      __syncthreads();
      if (t < 64){
        int qq = t>>3, c = t&7;
        float s = 0.f;
        for (int g=0; g<128; ++g) s += scr[(g*8+qq)*8 + c];
        out[O_RO + (size_t)b*256 + h*64 + t] = s;
        ro[h*64 + t] = s;
      }
      __syncthreads();
    }
  }

  // ntm_out epilogue: out[b,:] = partial(ctrl@oW1, from k_proj) + ro @ oW2 + oB
  {
    const int c = t & 255, kh = t >> 8;      // kh in {0..3}: split K=256 in quarters
    const float* P  = oW + ((size_t)(512 + kh*64))*256 + c;
    const float* rr = ro + kh*64;
    float a0=0.f,a1=0.f,a2=0.f,a3=0.f;
    #pragma unroll 4
    for (int k=0; k<64; k+=4){
      float4 rv = *(const float4*)&rr[k];
      a0 = fmaf(rv.x, P[(k+0)*256], a0);
      a1 = fmaf(rv.y, P[(k+1)*256], a1);
      a2 = fmaf(rv.z, P[(k+2)*256], a2);
      a3 = fmaf(rv.w, P[(k+3)*256], a3);
    }
    float* scr = (float*)slots;
    scr[t] = (a0+a1)+(a2+a3);
    __syncthreads();
    if (t < 256){
      size_t idx = (size_t)b*256 + t;
      out[idx] = out[idx] + scr[t] + scr[t+256] + scr[t+512] + scr[t+768] + oB[t];
    }
  }
}

// ---------------- launch ----------------

extern "C" void kernel_launch(void* const* d_in, const int* in_sizes, int n_in,
                              void* d_out, int out_size, void* d_ws, size_t ws_size,
                              hipStream_t stream) {
  (void)in_sizes; (void)n_in; (void)out_size; (void)ws_size;
  const float* ext    = (const float*)d_in[0];
  const float* prd    = (const float*)d_in[1];
  const float* prw    = (const float*)d_in[2];
  const float* pww    = (const float*)d_in[3];
  const float* mem0   = (const float*)d_in[4];
  const float* ctrlW  = (const float*)d_in[5];
  const float* ctrlB  = (const float*)d_in[6];
  const float* readW  = (const float*)d_in[7];
  const float* readB  = (const float*)d_in[8];
  const float* writeW = (const float*)d_in[9];
  const float* writeB = (const float*)d_in[10];
  const float* outW   = (const float*)d_in[11];
  const float* outB   = (const float*)d_in[12];
  float* out = (float*)d_out;
  float* ws  = (float*)d_ws;
  float* rp  = ws;                  // 71680 floats
  float* wp  = rp + 71680;          // 202752 floats

  k_proj<<<256,512,0,stream>>>(ext, prd, ctrlW, ctrlB, readW, readB, writeW, writeB, outW,
                               rp, wp, out);
  mega_kernel<<<256,1024,0,stream>>>(mem0, prw, pww, rp, wp, outW, outB, out);
}

// Round 8
// 441.253 us; speedup vs baseline: 1.4232x; 1.4232x over previous
//
#include <hip/hip_runtime.h>
#include <math.h>

#define EPSV 1e-8f

// d_out layout (floats): ntm_out[0], memory[65536], read_out[33619968],
// new_read_w[33685504], new_write_w[35782656]
#define O_MEM 65536
#define O_RO  33619968
#define O_NRW 33685504
#define O_NWW 35782656

__device__ __forceinline__ float sp_(float x){ return fmaxf(x,0.f) + log1pf(expf(-fabsf(x))); }
__device__ __forceinline__ float sg_(float x){ return 1.f/(1.f+expf(-x)); }

// ---------------- fused controller + projections + ntm_out partial ----------
// grid 256 (1 batch/block), 512 threads.
struct CM { const float* P; int S; float bv; float* dst; };

__device__ __forceinline__ CM cmap(int c, int b,
    const float* __restrict__ rW, const float* __restrict__ rB,
    const float* __restrict__ wW, const float* __restrict__ wB,
    const float* __restrict__ oW,
    float* __restrict__ rp, float* __restrict__ wp, float* __restrict__ out)
{
  CM m;
  if (c < 280){
    int h = c/70, j = c - h*70;
    m.P = rW + (size_t)h*35840 + j;  m.S = 70;
    m.bv = rB[c];
    m.dst = rp + ((size_t)h*256 + b)*70 + j;
  } else if (c < 1072){
    int c2 = c - 280, h = c2/198, j = c2 - h*198;
    m.P = wW + (size_t)h*101376 + j; m.S = 198;
    m.bv = wB[c2];
    m.dst = wp + ((size_t)h*256 + b)*198 + j;
  } else {
    int j = c - 1072;
    m.P = oW + j;                    m.S = 256;
    m.bv = 0.f;
    m.dst = out + (size_t)b*256 + j;
  }
  return m;
}

__global__ __launch_bounds__(512) void k_proj(
    const float* __restrict__ ext, const float* __restrict__ prd,
    const float* __restrict__ cW, const float* __restrict__ cB,
    const float* __restrict__ rW, const float* __restrict__ rB,
    const float* __restrict__ wW, const float* __restrict__ wB,
    const float* __restrict__ oW,
    float* __restrict__ rp, float* __restrict__ wp, float* __restrict__ out)
{
  __shared__ float ins[512];
  __shared__ float cs[512];
  const int t = threadIdx.x, b = blockIdx.x;
  ins[t] = (t < 256) ? ext[(size_t)b*256 + t] : prd[(size_t)b*256 + (t - 256)];
  __syncthreads();

  { // phase 1: ctrl col t, 4 split accumulators for ILP
    float a0=0.f, a1=0.f, a2=0.f, a3=0.f;
    const float* W = cW + t;
    #pragma unroll 4
    for (int k=0; k<512; k+=4){
      float4 iv = *(const float4*)&ins[k];
      a0 = fmaf(iv.x, W[(k+0)*512], a0);
      a1 = fmaf(iv.y, W[(k+1)*512], a1);
      a2 = fmaf(iv.z, W[(k+2)*512], a2);
      a3 = fmaf(iv.w, W[(k+3)*512], a3);
    }
    cs[t] = (a0+a1)+(a2+a3) + cB[t];
  }
  __syncthreads();

  { // phase 2: cols t and t+512 paired
    CM m0 = cmap(t,       b, rW,rB,wW,wB,oW, rp,wp,out);
    CM m1 = cmap(t + 512, b, rW,rB,wW,wB,oW, rp,wp,out);
    const float* P0 = m0.P; const int S0 = m0.S;
    const float* P1 = m1.P; const int S1 = m1.S;
    float a00=0.f,a01=0.f,a02=0.f,a03=0.f;
    float a10=0.f,a11=0.f,a12=0.f,a13=0.f;
    #pragma unroll 4
    for (int k=0; k<512; k+=4){
      float4 cv = *(const float4*)&cs[k];
      a00 = fmaf(cv.x, P0[(k+0)*S0], a00);
      a10 = fmaf(cv.x, P1[(k+0)*S1], a10);
      a01 = fmaf(cv.y, P0[(k+1)*S0], a01);
      a11 = fmaf(cv.y, P1[(k+1)*S1], a11);
      a02 = fmaf(cv.z, P0[(k+2)*S0], a02);
      a12 = fmaf(cv.z, P1[(k+2)*S1], a12);
      a03 = fmaf(cv.w, P0[(k+3)*S0], a03);
      a13 = fmaf(cv.w, P1[(k+3)*S1], a13);
    }
    *m0.dst = (a00+a01)+(a02+a03) + m0.bv;
    *m1.dst = (a10+a11)+(a12+a13) + m1.bv;

    if (t < 304){ // tail: cols 1024..1327
      CM m2 = cmap(t + 1024, b, rW,rB,wW,wB,oW, rp,wp,out);
      const float* P2 = m2.P; const int S2 = m2.S;
      float b0=0.f,b1=0.f,b2=0.f,b3=0.f;
      #pragma unroll 4
      for (int k=0; k<512; k+=4){
        float4 cv = *(const float4*)&cs[k];
        b0 = fmaf(cv.x, P2[(k+0)*S2], b0);
        b1 = fmaf(cv.y, P2[(k+1)*S2], b1);
        b2 = fmaf(cv.z, P2[(k+2)*S2], b2);
        b3 = fmaf(cv.w, P2[(k+3)*S2], b3);
      }
      *m2.dst = (b0+b1)+(b2+b3) + m2.bv;
    }
  }
}

// ---------------- mega kernel (512 threads, 3 slab traversals) --------------

__device__ __forceinline__ float blockMax(float v, float* red){
  #pragma unroll
  for (int o=32;o;o>>=1) v = fmaxf(v, __shfl_down(v,o,64));
  __syncthreads();
  if ((threadIdx.x & 63) == 0) red[threadIdx.x>>6] = v;
  __syncthreads();
  float m = red[0];
  #pragma unroll
  for (int i=1;i<8;i++) m = fmaxf(m, red[i]);
  return m;
}
__device__ __forceinline__ float blockSum(float v, float* red){
  #pragma unroll
  for (int o=32;o;o>>=1) v += __shfl_down(v,o,64);
  __syncthreads();
  if ((threadIdx.x & 63) == 0) red[threadIdx.x>>6] = v;
  __syncthreads();
  float s = red[0];
  #pragma unroll
  for (int i=1;i<8;i++) s += red[i];
  return s;
}

// NTM addressing over slot c[2048] (cos-sim on entry, final w on exit). 512 thr, 4/thread.
__device__ void addressing(float* c, const float* __restrict__ wprev, float* __restrict__ wout,
                           float beta, float g, float s0, float s1, float s2, float gam,
                           float* red, int t){
  int base = t*4;
  float lv[4];
  {
    float4 cv = *(const float4*)&c[base];
    lv[0]=beta*cv.x; lv[1]=beta*cv.y; lv[2]=beta*cv.z; lv[3]=beta*cv.w;
  }
  float mx = fmaxf(fmaxf(lv[0],lv[1]), fmaxf(lv[2],lv[3]));
  mx = blockMax(mx, red);
  float sm = 0.f;
  #pragma unroll
  for (int i=0;i<4;i++){ lv[i] = expf(lv[i]-mx); sm += lv[i]; }
  sm = blockSum(sm, red);
  float inv = 1.f/sm;
  float gi = 1.f - g;
  {
    float4 wp4 = *(const float4*)&wprev[base];
    lv[0] = g*lv[0]*inv + gi*wp4.x;
    lv[1] = g*lv[1]*inv + gi*wp4.y;
    lv[2] = g*lv[2]*inv + gi*wp4.z;
    lv[3] = g*lv[3]*inv + gi*wp4.w;
  }
  *(float4*)&c[base] = make_float4(lv[0],lv[1],lv[2],lv[3]);
  __syncthreads();
  float left  = c[(base+2047)&2047];
  float right = c[(base+4)&2047];
  __syncthreads();
  float pw[4]; float ps=0.f;
  #pragma unroll
  for (int i=0;i<4;i++){
    float wm1 = (i==0)? left  : lv[i-1];
    float wp1 = (i==3)? right : lv[i+1];
    float wsv = s0*wp1 + s1*lv[i] + s2*wm1;
    float p = expf(gam * logf(wsv + EPSV));
    pw[i]=p; ps+=p;
  }
  ps = blockSum(ps, red);
  float invp = 1.f/ps;
  float4 wo = make_float4(pw[0]*invp, pw[1]*invp, pw[2]*invp, pw[3]*invp);
  *(float4*)&c[base] = wo;
  *(float4*)&wout[base] = wo;
  __syncthreads();
}

// Pass A: one traversal of M0. Computes cos for read heads 0-3 (slots 0-3),
// write head 0 (slot 4), and 5 packed rank-1 aux scalars per row for head 1:
// aux = {S1, dA, dB, P1=2C1-2S2, P2=S3-2C2}. 4 lanes/row, no internal barriers.
__device__ __forceinline__ void cosA_pass(const float* __restrict__ gmb,
    float (*slots)[2048], float (*aux)[2048],
    const float* __restrict__ kr, const float* __restrict__ kw,
    const float* __restrict__ er, const float* __restrict__ aw,
    const float* __restrict__ kn, int t)
{
  const int row0 = t>>2, q = t&3, cb = q<<4;
  float4 kk[5][4];
  #pragma unroll
  for (int c=0;c<4;c++){
    #pragma unroll
    for (int j=0;j<4;j++) kk[c][j] = *(const float4*)&kr[c*64+cb+4*j];
  }
  #pragma unroll
  for (int j=0;j<4;j++) kk[4][j] = *(const float4*)&kw[cb+4*j];
  float4 K1[4], E0[4], A0[4];
  #pragma unroll
  for (int j=0;j<4;j++){
    K1[j] = *(const float4*)&kw[64+cb+4*j];
    E0[j] = *(const float4*)&er[cb+4*j];
    A0[j] = *(const float4*)&aw[cb+4*j];
  }
  float knl[5];
  #pragma unroll
  for (int c=0;c<5;c++) knl[c]=kn[c];

  #pragma unroll 2
  for (int it=0; it<16; ++it){
    const int row = (it<<7) + row0;
    const float4* src = (const float4*)(gmb + ((size_t)row<<6) + cb);
    float4 v[4];
    #pragma unroll
    for (int j=0;j<4;j++) v[j] = src[j];
    float acc0=0,acc1=0,acc2=0,acc3=0,acc4=0;
    float S1=0,dA=0,dB=0,S2=0,S3=0,C1=0,C2=0;
    #pragma unroll
    for (int j=0;j<4;j++){
#define COMP(f) { float m=v[j].f, k1v=K1[j].f, e0v=E0[j].f, a0v=A0[j].f; \
      float m2=m*m; float p=m*k1v; float q2=m2*e0v; float r=m*a0v; \
      acc0=fmaf(m,kk[0][j].f,acc0); acc1=fmaf(m,kk[1][j].f,acc1); \
      acc2=fmaf(m,kk[2][j].f,acc2); acc3=fmaf(m,kk[3][j].f,acc3); \
      acc4=fmaf(m,kk[4][j].f,acc4); \
      S1+=m2; dA+=p; dB=fmaf(p,e0v,dB); S2+=q2; S3=fmaf(q2,e0v,S3); \
      C1+=r; C2=fmaf(r,e0v,C2); }
      COMP(x) COMP(y) COMP(z) COMP(w)
#undef COMP
    }
#define RED(s) s+=__shfl_xor(s,1); s+=__shfl_xor(s,2);
    RED(acc0) RED(acc1) RED(acc2) RED(acc3) RED(acc4)
    RED(S1) RED(dA) RED(dB) RED(S2) RED(S3) RED(C1) RED(C2)
#undef RED
    float mn = sqrtf(S1);
    float av = acc0, kv = knl[0];
    if (q==1){ av=acc1; kv=knl[1]; }
    if (q==2){ av=acc2; kv=knl[2]; }
    if (q==3){ av=acc3; kv=knl[3]; }
    slots[q][row] = av/(mn*kv+EPSV);
    if (q==0) slots[4][row] = acc4/(mn*knl[4]+EPSV);
    if (q==1){ aux[0][row]=S1; aux[1][row]=dA; aux[2][row]=dB; }
    if (q==2){ aux[3][row]=2.f*(C1-S2); aux[4][row]=S3-2.f*C2; }
  }
}

// Pass B: one traversal; applies updates {0,1} in registers (M2), computes
// cos for write head 2 (slot 6) + 5 packed rank-1 aux scalars for head 3.
__device__ __forceinline__ void cosB_pass(const float* __restrict__ gmb,
    float (*slots)[2048], float (*aux)[2048],
    const float* __restrict__ kw,
    const float* __restrict__ er, const float* __restrict__ aw,
    const float* __restrict__ kn, int t)
{
  const int row0 = t>>2, q = t&3, cb = q<<4;
  float4 E0[4],A0[4],E1[4],A1[4],K2[4],K3[4],E2[4],A2[4];
  #pragma unroll
  for (int j=0;j<4;j++){
    E0[j]=*(const float4*)&er[cb+4*j];      A0[j]=*(const float4*)&aw[cb+4*j];
    E1[j]=*(const float4*)&er[64+cb+4*j];   A1[j]=*(const float4*)&aw[64+cb+4*j];
    K2[j]=*(const float4*)&kw[128+cb+4*j];  K3[j]=*(const float4*)&kw[192+cb+4*j];
    E2[j]=*(const float4*)&er[128+cb+4*j];  A2[j]=*(const float4*)&aw[128+cb+4*j];
  }
  const float kn6 = kn[6];
  #pragma unroll 2
  for (int it=0; it<16; ++it){
    const int row = (it<<7) + row0;
    const float4* src = (const float4*)(gmb + ((size_t)row<<6) + cb);
    float4 v[4];
    #pragma unroll
    for (int j=0;j<4;j++) v[j] = src[j];
    const float w0 = slots[4][row], w1 = slots[5][row];
    float acc2s=0,S1=0,dA=0,dB=0,S2=0,S3=0,C1=0,C2=0;
    #pragma unroll
    for (int j=0;j<4;j++){
#define COMP(f) { float m=v[j].f; \
      m = fmaf(-w0, fmaf(m,E0[j].f,-A0[j].f), m); \
      m = fmaf(-w1, fmaf(m,E1[j].f,-A1[j].f), m); \
      float e2v=E2[j].f; float m2=m*m; float p=m*K3[j].f; float q2=m2*e2v; float r=m*A2[j].f; \
      acc2s=fmaf(m,K2[j].f,acc2s); \
      S1+=m2; dA+=p; dB=fmaf(p,e2v,dB); S2+=q2; S3=fmaf(q2,e2v,S3); \
      C1+=r; C2=fmaf(r,e2v,C2); }
      COMP(x) COMP(y) COMP(z) COMP(w)
#undef COMP
    }
#define RED(s) s+=__shfl_xor(s,1); s+=__shfl_xor(s,2);
    RED(acc2s) RED(S1) RED(dA) RED(dB) RED(S2) RED(S3) RED(C1) RED(C2)
#undef RED
    if (q==0) slots[6][row] = acc2s/(sqrtf(S1)*kn6+EPSV);
    if (q==1){ aux[0][row]=S1; aux[1][row]=dA; aux[2][row]=dB; }
    if (q==2){ aux[3][row]=2.f*(C1-S2); aux[4][row]=S3-2.f*C2; }
  }
}

// Rank-1 cosine reconstruction: cos(M',k) where M' = M*(1-w*e) + w*a,
// from packed aux {S1,dA,dB,P1,P2}. dst[r] = cos; w from wSlot[r].
__device__ __forceinline__ void rank1_cos(float* dst, const float* wSlot,
    float (*aux)[2048], float K, float A, float knv, int t)
{
  #pragma unroll
  for (int i=0;i<4;i++){
    const int r = t + 512*i;
    const float w = wSlot[r];
    const float d = aux[1][r] + w*(K - aux[2][r]);
    float N = aux[0][r] + w*aux[3][r] + w*w*(aux[4][r] + A);
    N = fmaxf(N, 0.f);
    dst[r] = d/(sqrtf(N)*knv + EPSV);
  }
}

// Final pass: 8 lanes/row, 64 rows/iter, 32 iters. Reads raw rows, accumulates
// read vectors, applies 4 updates, writes final memory.
__device__ __forceinline__ void final_pass(const float* __restrict__ gmb,
    float (*slots)[2048], const float* __restrict__ er, const float* __restrict__ aw,
    float4 racc[4][2], float* __restrict__ gout, int t)
{
  const int row0 = t>>3, q = t&7, cb = q<<3;
  float4 ee[4][2], aa[4][2];
  #pragma unroll
  for (int h=0;h<4;h++){
    #pragma unroll
    for (int j=0;j<2;j++){
      ee[h][j] = *(const float4*)&er[h*64+cb+4*j];
      aa[h][j] = *(const float4*)&aw[h*64+cb+4*j];
    }
  }
  #pragma unroll 4
  for (int it=0; it<32; ++it){
    const int row = (it<<6) + row0;
    const float4* src = (const float4*)(gmb + ((size_t)row<<6) + cb);
    float4 v0 = src[0], v1 = src[1];
    #pragma unroll
    for (int h=0;h<4;h++){
      float wr = slots[h][row];
      racc[h][0].x = fmaf(wr, v0.x, racc[h][0].x);
      racc[h][0].y = fmaf(wr, v0.y, racc[h][0].y);
      racc[h][0].z = fmaf(wr, v0.z, racc[h][0].z);
      racc[h][0].w = fmaf(wr, v0.w, racc[h][0].w);
      racc[h][1].x = fmaf(wr, v1.x, racc[h][1].x);
      racc[h][1].y = fmaf(wr, v1.y, racc[h][1].y);
      racc[h][1].z = fmaf(wr, v1.z, racc[h][1].z);
      racc[h][1].w = fmaf(wr, v1.w, racc[h][1].w);
    }
    #pragma unroll
    for (int h=0;h<4;h++){
      float w = slots[4+h][row];
      v0.x = fmaf(-w, fmaf(v0.x, ee[h][0].x, -aa[h][0].x), v0.x);
      v0.y = fmaf(-w, fmaf(v0.y, ee[h][0].y, -aa[h][0].y), v0.y);
      v0.z = fmaf(-w, fmaf(v0.z, ee[h][0].z, -aa[h][0].z), v0.z);
      v0.w = fmaf(-w, fmaf(v0.w, ee[h][0].w, -aa[h][0].w), v0.w);
      v1.x = fmaf(-w, fmaf(v1.x, ee[h][1].x, -aa[h][1].x), v1.x);
      v1.y = fmaf(-w, fmaf(v1.y, ee[h][1].y, -aa[h][1].y), v1.y);
      v1.z = fmaf(-w, fmaf(v1.z, ee[h][1].z, -aa[h][1].z), v1.z);
      v1.w = fmaf(-w, fmaf(v1.w, ee[h][1].w, -aa[h][1].w), v1.w);
    }
    float4* dst = (float4*)(gout + ((size_t)row<<6) + cb);
    dst[0]=v0; dst[1]=v1;
  }
}

__global__ __launch_bounds__(512) void mega_kernel(
    const float* __restrict__ mem0, const float* __restrict__ prw, const float* __restrict__ pww,
    const float* __restrict__ rp, const float* __restrict__ wp,
    const float* __restrict__ oW, const float* __restrict__ oB, float* __restrict__ out)
{
  const int b = blockIdx.x, t = threadIdx.x;
  __shared__ float slots[8][2048];   // 64 KB: 0-3 cos_r->w_r ; 4-7 cos_w->w_w
  __shared__ float aux[5][2048];     // 40 KB: packed rank-1 scalars {S1,dA,dB,P1,P2}
  __shared__ float kr[256], kw[256], er[256], aw[256];
  __shared__ float sBeta[8], sG[8], sGam[8], sKn[8], sS0[8], sS1[8], sS2[8];
  __shared__ float red[8];
  __shared__ float ro[256];          // read_out for the ntm_out epilogue

  if (t < 256){ // activations: idx 0-3 read heads, 4-7 write heads
    int h = t>>6, m = t&63;
    kr[t] = rp[((size_t)h*256 + b)*70 + m];
    const float* wph = wp + ((size_t)h*256 + b)*198;
    kw[t] = wph[m];
    er[t] = sg_(wph[70+m]);
    aw[t] = tanhf(wph[134+m]);
    if (t < 8){
      int hh = t & 3;
      const float* p = (t>=4) ? (wp + ((size_t)hh*256+b)*198) : (rp + ((size_t)hh*256+b)*70);
      sBeta[t] = sp_(p[64]);
      sG[t]    = sg_(p[65]);
      float a0=p[66], a1=p[67], a2=p[68];
      float mx = fmaxf(a0, fmaxf(a1,a2));
      float e0=expf(a0-mx), e1=expf(a1-mx), e2=expf(a2-mx);
      float inv = 1.f/(e0+e1+e2);
      sS0[t]=e0*inv; sS1[t]=e1*inv; sS2[t]=e2*inv;
      sGam[t]  = 1.f + sp_(p[69]);
    }
  }
  __syncthreads();
  if (t < 8){
    const float* kv = (t>=4) ? (kw + (t&3)*64) : (kr + (t&3)*64);
    float s=0.f;
    for (int m=0;m<64;m++) s = fmaf(kv[m],kv[m],s);
    sKn[t] = sqrtf(s);
  }
  __syncthreads();

  const float* gmb = mem0 + (size_t)b*131072;

  // Traversal 1: cos r0-3 (slots 0-3) + w0 (slot 4) + rank-1 aux for w1
  cosA_pass(gmb, slots, aux, kr,kw,er,aw,sKn, t);
  __syncthreads();
  #pragma unroll 1
  for (int h=0;h<4;h++)
    addressing(slots[h], prw + ((size_t)h*256+b)*2048, out + O_NRW + ((size_t)h*256+b)*2048,
               sBeta[h], sG[h], sS0[h], sS1[h], sS2[h], sGam[h], red, t);
  addressing(slots[4], pww + (size_t)b*2048, out + O_NWW + (size_t)b*2048,
             sBeta[4], sG[4], sS0[4], sS1[4], sS2[4], sGam[4], red, t);

  // w1 via rank-1 reconstruction (no traversal)
  {
    float K01=0.f, A00=0.f;
    for (int m=0;m<64;m++){ float av=aw[m]; K01=fmaf(av,kw[64+m],K01); A00=fmaf(av,av,A00); }
    rank1_cos(slots[5], slots[4], aux, K01, A00, sKn[5], t);
  }
  __syncthreads();
  addressing(slots[5], pww + ((size_t)256+b)*2048, out + O_NWW + ((size_t)256+b)*2048,
             sBeta[5], sG[5], sS0[5], sS1[5], sS2[5], sGam[5], red, t);

  // Traversal 2: updates {0,1} in regs -> cos w2 (slot 6) + rank-1 aux for w3
  cosB_pass(gmb, slots, aux, kw,er,aw,sKn, t);
  __syncthreads();
  addressing(slots[6], pww + ((size_t)512+b)*2048, out + O_NWW + ((size_t)512+b)*2048,
             sBeta[6], sG[6], sS0[6], sS1[6], sS2[6], sGam[6], red, t);

  // w3 via rank-1 reconstruction (no traversal)
  {
    float K23=0.f, A22=0.f;
    for (int m=0;m<64;m++){ float av=aw[128+m]; K23=fmaf(av,kw[192+m],K23); A22=fmaf(av,av,A22); }
    rank1_cos(slots[7], slots[6], aux, K23, A22, sKn[7], t);
  }
  __syncthreads();
  addressing(slots[7], pww + ((size_t)768+b)*2048, out + O_NWW + ((size_t)768+b)*2048,
             sBeta[7], sG[7], sS0[7], sS1[7], sS2[7], sGam[7], red, t);

  // Traversal 3: reads on raw rows + all 4 updates + write memory
  float4 racc[4][2];
  #pragma unroll
  for (int h=0;h<4;h++){ racc[h][0]=make_float4(0,0,0,0); racc[h][1]=make_float4(0,0,0,0); }
  final_pass(gmb, slots, er, aw, racc, out + O_MEM + (size_t)b*131072, t);
  __syncthreads();

  // reads reduction: thread t = row0*8+q holds cols q*8..q*8+7 partials
  {
    float* scr = (float*)slots;
    #pragma unroll 1
    for (int h=0;h<4;h++){
      *(float4*)&scr[t*8]   = racc[h][0];
      *(float4*)&scr[t*8+4] = racc[h][1];
      __syncthreads();
      if (t < 64){
        int qq = t>>3, c = t&7;
        float s = 0.f;
        for (int g=0; g<64; ++g) s += scr[(g*8+qq)*8 + c];
        out[O_RO + (size_t)b*256 + h*64 + t] = s;
        ro[h*64 + t] = s;
      }
      __syncthreads();
    }
  }

  // ntm_out epilogue: out[b,:] = partial(ctrl@oW1, from k_proj) + ro @ oW2 + oB
  {
    const int c = t & 255, kh = t >> 8;      // kh in {0,1}: split K=256 in halves
    const float* P  = oW + ((size_t)(512 + kh*128))*256 + c;
    const float* rr = ro + kh*128;
    float a0=0.f,a1=0.f,a2=0.f,a3=0.f;
    #pragma unroll 4
    for (int k=0; k<128; k+=4){
      float4 rv = *(const float4*)&rr[k];
      a0 = fmaf(rv.x, P[(k+0)*256], a0);
      a1 = fmaf(rv.y, P[(k+1)*256], a1);
      a2 = fmaf(rv.z, P[(k+2)*256], a2);
      a3 = fmaf(rv.w, P[(k+3)*256], a3);
    }
    float* scr = (float*)slots;
    scr[t] = (a0+a1)+(a2+a3);
    __syncthreads();
    if (t < 256){
      size_t idx = (size_t)b*256 + t;
      out[idx] = out[idx] + scr[t] + scr[t+256] + oB[t];
    }
  }
}

// ---------------- launch ----------------

extern "C" void kernel_launch(void* const* d_in, const int* in_sizes, int n_in,
                              void* d_out, int out_size, void* d_ws, size_t ws_size,
                              hipStream_t stream) {
  (void)in_sizes; (void)n_in; (void)out_size; (void)ws_size;
  const float* ext    = (const float*)d_in[0];
  const float* prd    = (const float*)d_in[1];
  const float* prw    = (const float*)d_in[2];
  const float* pww    = (const float*)d_in[3];
  const float* mem0   = (const float*)d_in[4];
  const float* ctrlW  = (const float*)d_in[5];
  const float* ctrlB  = (const float*)d_in[6];
  const float* readW  = (const float*)d_in[7];
  const float* readB  = (const float*)d_in[8];
  const float* writeW = (const float*)d_in[9];
  const float* writeB = (const float*)d_in[10];
  const float* outW   = (const float*)d_in[11];
  const float* outB   = (const float*)d_in[12];
  float* out = (float*)d_out;
  float* ws  = (float*)d_ws;
  float* rp  = ws;                  // 71680 floats
  float* wp  = rp + 71680;          // 202752 floats

  k_proj<<<256,512,0,stream>>>(ext, prd, ctrlW, ctrlB, readW, readB, writeW, writeB, outW,
                               rp, wp, out);
  mega_kernel<<<256,512,0,stream>>>(mem0, prw, pww, rp, wp, outW, outB, out);
}